// Round 4
// baseline (667.250 us; speedup 1.0000x reference)
//
#include <hip/hip_runtime.h>
#include <hip/hip_bf16.h>
#include <cstdint>
#include <cstddef>

// AttentionModule N=65536, C=D=512, L=16.
// Math (L-expand makes softmax uniform; attention branch cancels):
//   pos  = relu(features @ Wk^T)
//   pv   = sigmoid(pos @ Wvc^T) * pos
//   hmid = relu(bn1(features2 @ Wv1^T))
//   out  = relu(bn2(hmid @ Wv2^T)) + pv
//
// Single fused kernel, one 64-row panel per block, all 4 GEMMs chained:
//   stage f->P1, f2->P2 (interleaved, one latency exposure)
//   GEMM1 (A=P1:f)    -> pos -> P1
//   GEMM2 (A=P1:pos)  -> pv in REGISTERS (no HBM round-trip)
//   GEMM3 (A=P2:f2)   -> hmid -> P2
//   GEMM4 (A=P2:hmid) -> relu(bn2)+pv -> out
// B fragments stream from global (weights L2-resident bf16); K-loop is
// barrier-free, fully unrolled, mov-free double-buffered (a0/a1, b0/b1).

#define DIM 512
#define NROWS 65536
#define MBLK 64

typedef __bf16 bf16;
typedef __attribute__((ext_vector_type(8))) __bf16 bf16x8;
typedef __attribute__((ext_vector_type(4))) __bf16 bf16x4;
typedef __attribute__((ext_vector_type(4))) float f32x4;

__device__ __forceinline__ float sigmoidf_(float x) {
  return 1.0f / (1.0f + __expf(-x));
}

// Swizzled LDS byte offset into a [64][512] bf16 panel (row stride 1024 B).
// XOR of (row&15)<<4 spreads an MFMA A-fragment's 16 rows across 16 distinct
// 16B slots -> max 2-way bank aliasing on ds_read_b128 (free).
__device__ __forceinline__ int lds_off(int row, int cb) {
  return row * (DIM * 2) + (cb ^ ((row & 15) << 4));
}

// A-fragment read: rows i*16+lr, k-chunk kb + kq*8 elems (16B).
__device__ __forceinline__ bf16x8 lda(const char* As, int i, int lr, int kq,
                                      int kb) {
  return *(const bf16x8*)(As + (i * 16 + lr) * (DIM * 2) +
                          ((kb * 2 + kq * 16) ^ (lr << 4)));
}

// fp32 -> bf16 elementwise, vectorized x4. n4 = n/4.
__global__ __launch_bounds__(256) void cvt_f32_bf16(
    const float* __restrict__ s, bf16* __restrict__ d, int n4) {
  int i = blockIdx.x * 256 + threadIdx.x;
  if (i < n4) {
    f32x4 v = ((const f32x4*)s)[i];
    bf16x4 o;
    o[0] = (bf16)v[0]; o[1] = (bf16)v[1]; o[2] = (bf16)v[2]; o[3] = (bf16)v[3];
    ((bf16x4*)d)[i] = o;
  }
}

// Stage TWO 64x512 fp32 panels -> bf16, swizzled, into LDS. 512 threads.
// Interleaved so both HBM streams are in flight together.
__device__ __forceinline__ void stage2(char* PA, const float* __restrict__ ga,
                                       char* PB, const float* __restrict__ gb,
                                       int t) {
#pragma unroll
  for (int it = 0; it < 8; ++it) {
    int c = it * 512 + t;  // 16B-chunk id, 0..4095
    f32x4 a0 = *(const f32x4*)(ga + (size_t)c * 8);
    f32x4 a1 = *(const f32x4*)(ga + (size_t)c * 8 + 4);
    f32x4 b0 = *(const f32x4*)(gb + (size_t)c * 8);
    f32x4 b1 = *(const f32x4*)(gb + (size_t)c * 8 + 4);
    bf16x8 oa, ob;
    oa[0] = (bf16)a0[0]; oa[1] = (bf16)a0[1]; oa[2] = (bf16)a0[2]; oa[3] = (bf16)a0[3];
    oa[4] = (bf16)a1[0]; oa[5] = (bf16)a1[1]; oa[6] = (bf16)a1[2]; oa[7] = (bf16)a1[3];
    ob[0] = (bf16)b0[0]; ob[1] = (bf16)b0[1]; ob[2] = (bf16)b0[2]; ob[3] = (bf16)b0[3];
    ob[4] = (bf16)b1[0]; ob[5] = (bf16)b1[1]; ob[6] = (bf16)b1[2]; ob[7] = (bf16)b1[3];
    int off = lds_off(c >> 6, (c & 63) * 16);
    *(bf16x8*)(PA + off) = oa;
    *(bf16x8*)(PB + off) = ob;
  }
}

// Per-wave 64(M)x64(N) tile: acc += As(64x512 bf16, swizzled) @ W[wn:wn+64,:]^T.
// Mov-free double-buffered pipeline; B loads issued right after their
// consumers (WAR) so the scheduler gives ~1-iteration prefetch distance.
__device__ __forceinline__ void gemm_core(f32x4 (&acc)[4][4], const char* As,
                                          const bf16* __restrict__ W, int lr,
                                          int kq, int wn) {
  const bf16* bp = W + (size_t)(wn + lr) * DIM + kq * 8;
  bf16x8 a0[4], a1[4], b0[4], b1[4];
#pragma unroll
  for (int j = 0; j < 4; j++) b0[j] = *(const bf16x8*)(bp + j * 16 * DIM);
#pragma unroll
  for (int j = 0; j < 4; j++) b1[j] = *(const bf16x8*)(bp + j * 16 * DIM + 32);
#pragma unroll
  for (int i = 0; i < 4; i++) a0[i] = lda(As, i, lr, kq, 0);
#pragma unroll
  for (int kb = 0; kb < DIM; kb += 64) {
    // ---- half 0: consume a0/b0 (k=kb) ----
#pragma unroll
    for (int i = 0; i < 4; i++) a1[i] = lda(As, i, lr, kq, kb + 32);
#pragma unroll
    for (int i = 0; i < 4; i++)
#pragma unroll
      for (int j = 0; j < 4; j++)
        acc[i][j] = __builtin_amdgcn_mfma_f32_16x16x32_bf16(a0[i], b0[j],
                                                            acc[i][j], 0, 0, 0);
    if (kb + 64 < DIM) {
#pragma unroll
      for (int j = 0; j < 4; j++)
        b0[j] = *(const bf16x8*)(bp + j * 16 * DIM + kb + 64);
#pragma unroll
      for (int i = 0; i < 4; i++) a0[i] = lda(As, i, lr, kq, kb + 64);
    }
    // ---- half 1: consume a1/b1 (k=kb+32) ----
#pragma unroll
    for (int i = 0; i < 4; i++)
#pragma unroll
      for (int j = 0; j < 4; j++)
        acc[i][j] = __builtin_amdgcn_mfma_f32_16x16x32_bf16(a1[i], b1[j],
                                                            acc[i][j], 0, 0, 0);
    if (kb + 96 < DIM) {
#pragma unroll
      for (int j = 0; j < 4; j++)
        b1[j] = *(const bf16x8*)(bp + j * 16 * DIM + kb + 96);
    }
  }
}

__device__ __forceinline__ void zero_acc(f32x4 (&acc)[4][4]) {
#pragma unroll
  for (int i = 0; i < 4; i++)
#pragma unroll
    for (int j = 0; j < 4; j++) acc[i][j] = (f32x4){0.f, 0.f, 0.f, 0.f};
}

__global__ __launch_bounds__(512, 2) void fused_all(
    const float* __restrict__ f, const float* __restrict__ f2,
    const bf16* __restrict__ Wk, const bf16* __restrict__ Wvc,
    const bf16* __restrict__ Wv1, const bf16* __restrict__ Wv2,
    float* __restrict__ out, const float* __restrict__ bg1,
    const float* __restrict__ bb1, const float* __restrict__ bm1,
    const float* __restrict__ bv1, const float* __restrict__ bg2,
    const float* __restrict__ bb2, const float* __restrict__ bm2,
    const float* __restrict__ bv2) {
  __shared__ __align__(16) char P1[MBLK * DIM * 2];  // 64 KiB
  __shared__ __align__(16) char P2[MBLK * DIM * 2];  // 64 KiB

  const int t = threadIdx.x;
  const int lane = t & 63;
  const int lr = lane & 15;
  const int kq = lane >> 4;
  const int wn = (t >> 6) * 64;
  const size_t m0 = (size_t)blockIdx.x * MBLK;

  stage2(P1, f + m0 * DIM, P2, f2 + m0 * DIM, t);
  __syncthreads();

  f32x4 acc[4][4];

  // GEMM1: pos = relu(f @ Wk^T)
  zero_acc(acc);
  gemm_core(acc, P1, Wk, lr, kq, wn);
  __syncthreads();  // all waves done reading f-panel
#pragma unroll
  for (int i = 0; i < 4; i++)
#pragma unroll
    for (int j = 0; j < 4; j++)
#pragma unroll
      for (int r = 0; r < 4; r++) {
        int m = i * 16 + kq * 4 + r;
        int n = wn + j * 16 + lr;
        *(bf16*)(P1 + lds_off(m, n * 2)) = (bf16)fmaxf(acc[i][j][r], 0.f);
      }
  __syncthreads();

  // GEMM2: pv = sigmoid(pos @ Wvc^T) * pos  (kept in registers)
  zero_acc(acc);
  gemm_core(acc, P1, Wvc, lr, kq, wn);
  bf16x4 pvr[4][4];
#pragma unroll
  for (int i = 0; i < 4; i++)
#pragma unroll
    for (int j = 0; j < 4; j++)
#pragma unroll
      for (int r = 0; r < 4; r++) {
        int m = i * 16 + kq * 4 + r;
        int n = wn + j * 16 + lr;
        float p = (float)(*(const bf16*)(P1 + lds_off(m, n * 2)));
        pvr[i][j][r] = (bf16)(sigmoidf_(acc[i][j][r]) * p);
      }

  // GEMM3: hmid = relu(bn1(f2 @ Wv1^T))   (P2 stable since stage; no barrier)
  zero_acc(acc);
  gemm_core(acc, P2, Wv1, lr, kq, wn);
  float iv1[4], bc1[4];
#pragma unroll
  for (int j = 0; j < 4; j++) {
    int c = wn + j * 16 + lr;
    float s = bg1[c] * rsqrtf(bv1[c] + 1e-5f);
    iv1[j] = s;
    bc1[j] = bb1[c] - bm1[c] * s;
  }
  __syncthreads();  // all waves done reading f2-panel
#pragma unroll
  for (int i = 0; i < 4; i++)
#pragma unroll
    for (int j = 0; j < 4; j++)
#pragma unroll
      for (int r = 0; r < 4; r++) {
        int m = i * 16 + kq * 4 + r;
        int n = wn + j * 16 + lr;
        float v = fmaxf(acc[i][j][r] * iv1[j] + bc1[j], 0.f);
        *(bf16*)(P2 + lds_off(m, n * 2)) = (bf16)v;
      }
  __syncthreads();

  // GEMM4: out = relu(bn2(hmid @ Wv2^T)) + pv
  zero_acc(acc);
  gemm_core(acc, P2, Wv2, lr, kq, wn);
  float iv2[4], bc2[4];
#pragma unroll
  for (int j = 0; j < 4; j++) {
    int c = wn + j * 16 + lr;
    float s = bg2[c] * rsqrtf(bv2[c] + 1e-5f);
    iv2[j] = s;
    bc2[j] = bb2[c] - bm2[c] * s;
  }
#pragma unroll
  for (int i = 0; i < 4; i++)
#pragma unroll
    for (int j = 0; j < 4; j++)
#pragma unroll
      for (int r = 0; r < 4; r++) {
        int m = i * 16 + kq * 4 + r;
        int n = wn + j * 16 + lr;
        float v = fmaxf(acc[i][j][r] * iv2[j] + bc2[j], 0.f) + (float)pvr[i][j][r];
        out[(m0 + m) * DIM + n] = v;
      }
}

extern "C" void kernel_launch(void* const* d_in, const int* in_sizes, int n_in,
                              void* d_out, int out_size, void* d_ws,
                              size_t ws_size, hipStream_t stream) {
  const float* features  = (const float*)d_in[0];
  const float* features2 = (const float*)d_in[1];
  const float* Wk  = (const float*)d_in[2];
  const float* Wv1 = (const float*)d_in[3];
  const float* Wv2 = (const float*)d_in[4];
  const float* g1 = (const float*)d_in[5];
  const float* b1 = (const float*)d_in[6];
  const float* m1 = (const float*)d_in[7];
  const float* v1 = (const float*)d_in[8];
  const float* g2 = (const float*)d_in[9];
  const float* b2 = (const float*)d_in[10];
  const float* m2 = (const float*)d_in[11];
  const float* v2 = (const float*)d_in[12];
  // d_in[13] Wa, d_in[14] Wqk: cancelled, unused.
  const float* Wvc = (const float*)d_in[15];
  float* out = (float*)d_out;

  // ws (bf16): wk | wvc | wv1 | wv2  = 2 MiB total.
  bf16* wkb  = (bf16*)d_ws;
  bf16* wvcb = wkb + (size_t)DIM * DIM;
  bf16* wv1b = wvcb + (size_t)DIM * DIM;
  bf16* wv2b = wv1b + (size_t)DIM * DIM;

  {
    int n4 = DIM * DIM / 4;  // 65536
    dim3 cg(n4 / 256), cb(256);
    cvt_f32_bf16<<<cg, cb, 0, stream>>>(Wk, wkb, n4);
    cvt_f32_bf16<<<cg, cb, 0, stream>>>(Wvc, wvcb, n4);
    cvt_f32_bf16<<<cg, cb, 0, stream>>>(Wv1, wv1b, n4);
    cvt_f32_bf16<<<cg, cb, 0, stream>>>(Wv2, wv2b, n4);
  }

  dim3 grid(NROWS / MBLK);  // 1024 blocks, 512 threads (8 waves)
  dim3 block(512);
  fused_all<<<grid, block, 0, stream>>>(features, features2, wkb, wvcb, wv1b,
                                        wv2b, out, g1, b1, m1, v1, g2, b2, m2,
                                        v2);
}

// Round 5
// 664.482 us; speedup vs baseline: 1.0042x; 1.0042x over previous
//
#include <hip/hip_runtime.h>
#include <hip/hip_bf16.h>
#include <cstdint>
#include <cstddef>

// AttentionModule N=65536, C=D=512, L=16.
// Math (L-expand makes softmax uniform; attention branch cancels):
//   pos  = relu(features @ Wk^T)
//   pv   = sigmoid(pos @ Wvc^T) * pos
//   hmid = relu(bn1(features2 @ Wv1^T))
//   out  = relu(bn2(hmid @ Wv2^T)) + pv
//
// Single fused kernel, 64-row panel per block, all 4 GEMMs chained in LDS.
// Round-5 shape change vs round 4 (which spilled: VGPR capped 128, demand
// ~190 -> 176 MB scratch writes): block = 1024 threads (16 waves), per-wave
// tile 64x32 -> ~105 VGPRs, no spill, 4 waves/SIMD (2x occupancy).

#define DIM 512
#define NROWS 65536
#define MBLK 64

typedef __bf16 bf16;
typedef __attribute__((ext_vector_type(8))) __bf16 bf16x8;
typedef __attribute__((ext_vector_type(4))) __bf16 bf16x4;
typedef __attribute__((ext_vector_type(4))) float f32x4;

__device__ __forceinline__ float sigmoidf_(float x) {
  return 1.0f / (1.0f + __expf(-x));
}

// Swizzled LDS byte offset into a [64][512] bf16 panel (row stride 1024 B).
// XOR of (row&15)<<4 spreads an MFMA A-fragment's 16 rows across 16 distinct
// 16B slots -> max 2-way bank aliasing on ds_read_b128 (free).
__device__ __forceinline__ int lds_off(int row, int cb) {
  return row * (DIM * 2) + (cb ^ ((row & 15) << 4));
}

// A-fragment read: rows i*16+lr, k-chunk kb + kq*8 elems (16B).
__device__ __forceinline__ bf16x8 lda(const char* As, int i, int lr, int kq,
                                      int kb) {
  return *(const bf16x8*)(As + (i * 16 + lr) * (DIM * 2) +
                          ((kb * 2 + kq * 16) ^ (lr << 4)));
}

// fp32 -> bf16 for the 4 weight matrices in ONE launch.
// grid = 4 * 256 blocks of 256 threads; 65536 x4-chunks per matrix.
__global__ __launch_bounds__(256) void cvt4_f32_bf16(
    const float* __restrict__ s0, const float* __restrict__ s1,
    const float* __restrict__ s2, const float* __restrict__ s3,
    bf16* __restrict__ d0, bf16* __restrict__ d1, bf16* __restrict__ d2,
    bf16* __restrict__ d3) {
  int mat = blockIdx.x >> 8;
  int i = (blockIdx.x & 255) * 256 + threadIdx.x;
  const float* s = mat == 0 ? s0 : mat == 1 ? s1 : mat == 2 ? s2 : s3;
  bf16* d = mat == 0 ? d0 : mat == 1 ? d1 : mat == 2 ? d2 : d3;
  f32x4 v = ((const f32x4*)s)[i];
  bf16x4 o;
  o[0] = (bf16)v[0]; o[1] = (bf16)v[1]; o[2] = (bf16)v[2]; o[3] = (bf16)v[3];
  ((bf16x4*)d)[i] = o;
}

// Stage TWO 64x512 fp32 panels -> bf16, swizzled, into LDS. 1024 threads.
// Interleaved so both HBM streams are in flight together.
__device__ __forceinline__ void stage2(char* PA, const float* __restrict__ ga,
                                       char* PB, const float* __restrict__ gb,
                                       int t) {
#pragma unroll
  for (int it = 0; it < 4; ++it) {
    int c = it * 1024 + t;  // 16B-chunk id, 0..4095
    f32x4 a0 = *(const f32x4*)(ga + (size_t)c * 8);
    f32x4 a1 = *(const f32x4*)(ga + (size_t)c * 8 + 4);
    f32x4 b0 = *(const f32x4*)(gb + (size_t)c * 8);
    f32x4 b1 = *(const f32x4*)(gb + (size_t)c * 8 + 4);
    bf16x8 oa, ob;
    oa[0] = (bf16)a0[0]; oa[1] = (bf16)a0[1]; oa[2] = (bf16)a0[2]; oa[3] = (bf16)a0[3];
    oa[4] = (bf16)a1[0]; oa[5] = (bf16)a1[1]; oa[6] = (bf16)a1[2]; oa[7] = (bf16)a1[3];
    ob[0] = (bf16)b0[0]; ob[1] = (bf16)b0[1]; ob[2] = (bf16)b0[2]; ob[3] = (bf16)b0[3];
    ob[4] = (bf16)b1[0]; ob[5] = (bf16)b1[1]; ob[6] = (bf16)b1[2]; ob[7] = (bf16)b1[3];
    int off = lds_off(c >> 6, (c & 63) * 16);
    *(bf16x8*)(PA + off) = oa;
    *(bf16x8*)(PB + off) = ob;
  }
}

// Per-wave 64(M)x32(N) tile: acc += As(64x512 bf16, swizzled) @ W[wn:wn+32,:]^T.
// Mov-free double-buffered pipeline (a0/a1 half-step, b0/b1 one-step ahead).
__device__ __forceinline__ void gemm_core(f32x4 (&acc)[4][2], const char* As,
                                          const bf16* __restrict__ W, int lr,
                                          int kq, int wn) {
  const bf16* bp = W + (size_t)(wn + lr) * DIM + kq * 8;
  bf16x8 a0[4], a1[4], b0[2], b1[2];
#pragma unroll
  for (int j = 0; j < 2; j++) b0[j] = *(const bf16x8*)(bp + j * 16 * DIM);
#pragma unroll
  for (int j = 0; j < 2; j++) b1[j] = *(const bf16x8*)(bp + j * 16 * DIM + 32);
#pragma unroll
  for (int i = 0; i < 4; i++) a0[i] = lda(As, i, lr, kq, 0);
#pragma unroll
  for (int kb = 0; kb < DIM; kb += 64) {
    // ---- half 0: consume a0/b0 (k=kb) ----
#pragma unroll
    for (int i = 0; i < 4; i++) a1[i] = lda(As, i, lr, kq, kb + 32);
#pragma unroll
    for (int i = 0; i < 4; i++)
#pragma unroll
      for (int j = 0; j < 2; j++)
        acc[i][j] = __builtin_amdgcn_mfma_f32_16x16x32_bf16(a0[i], b0[j],
                                                            acc[i][j], 0, 0, 0);
    if (kb + 64 < DIM) {
#pragma unroll
      for (int j = 0; j < 2; j++)
        b0[j] = *(const bf16x8*)(bp + j * 16 * DIM + kb + 64);
#pragma unroll
      for (int i = 0; i < 4; i++) a0[i] = lda(As, i, lr, kq, kb + 64);
    }
    // ---- half 1: consume a1/b1 (k=kb+32) ----
#pragma unroll
    for (int i = 0; i < 4; i++)
#pragma unroll
      for (int j = 0; j < 2; j++)
        acc[i][j] = __builtin_amdgcn_mfma_f32_16x16x32_bf16(a1[i], b1[j],
                                                            acc[i][j], 0, 0, 0);
    if (kb + 96 < DIM) {
#pragma unroll
      for (int j = 0; j < 2; j++)
        b1[j] = *(const bf16x8*)(bp + j * 16 * DIM + kb + 96);
    }
  }
}

__device__ __forceinline__ void zero_acc(f32x4 (&acc)[4][2]) {
#pragma unroll
  for (int i = 0; i < 4; i++)
#pragma unroll
    for (int j = 0; j < 2; j++) acc[i][j] = (f32x4){0.f, 0.f, 0.f, 0.f};
}

__global__ __launch_bounds__(1024, 1) void fused_all(
    const float* __restrict__ f, const float* __restrict__ f2,
    const bf16* __restrict__ Wk, const bf16* __restrict__ Wvc,
    const bf16* __restrict__ Wv1, const bf16* __restrict__ Wv2,
    float* __restrict__ out, const float* __restrict__ bg1,
    const float* __restrict__ bb1, const float* __restrict__ bm1,
    const float* __restrict__ bv1, const float* __restrict__ bg2,
    const float* __restrict__ bb2, const float* __restrict__ bm2,
    const float* __restrict__ bv2) {
  __shared__ __align__(16) char P1[MBLK * DIM * 2];  // 64 KiB
  __shared__ __align__(16) char P2[MBLK * DIM * 2];  // 64 KiB

  const int t = threadIdx.x;
  const int lane = t & 63;
  const int lr = lane & 15;
  const int kq = lane >> 4;
  const int wn = (t >> 6) * 32;  // 16 waves x 32 cols = 512
  const size_t m0 = (size_t)blockIdx.x * MBLK;

  stage2(P1, f + m0 * DIM, P2, f2 + m0 * DIM, t);
  __syncthreads();

  f32x4 acc[4][2];

  // GEMM1: pos = relu(f @ Wk^T)
  zero_acc(acc);
  gemm_core(acc, P1, Wk, lr, kq, wn);
  __syncthreads();  // all waves done reading f-panel
#pragma unroll
  for (int i = 0; i < 4; i++)
#pragma unroll
    for (int j = 0; j < 2; j++)
#pragma unroll
      for (int r = 0; r < 4; r++) {
        int m = i * 16 + kq * 4 + r;
        int n = wn + j * 16 + lr;
        *(bf16*)(P1 + lds_off(m, n * 2)) = (bf16)fmaxf(acc[i][j][r], 0.f);
      }
  __syncthreads();

  // GEMM2: pv = sigmoid(pos @ Wvc^T) * pos  (kept in registers)
  zero_acc(acc);
  gemm_core(acc, P1, Wvc, lr, kq, wn);
  bf16x4 pvr[4][2];
#pragma unroll
  for (int i = 0; i < 4; i++)
#pragma unroll
    for (int j = 0; j < 2; j++)
#pragma unroll
      for (int r = 0; r < 4; r++) {
        int m = i * 16 + kq * 4 + r;
        int n = wn + j * 16 + lr;
        float p = (float)(*(const bf16*)(P1 + lds_off(m, n * 2)));
        pvr[i][j][r] = (bf16)(sigmoidf_(acc[i][j][r]) * p);
      }

  // GEMM3: hmid = relu(bn1(f2 @ Wv1^T))   (P2 stable since stage; no barrier)
  zero_acc(acc);
  gemm_core(acc, P2, Wv1, lr, kq, wn);
  float iv1[2], bc1[2];
#pragma unroll
  for (int j = 0; j < 2; j++) {
    int c = wn + j * 16 + lr;
    float s = bg1[c] * rsqrtf(bv1[c] + 1e-5f);
    iv1[j] = s;
    bc1[j] = bb1[c] - bm1[c] * s;
  }
  __syncthreads();  // all waves done reading f2-panel
#pragma unroll
  for (int i = 0; i < 4; i++)
#pragma unroll
    for (int j = 0; j < 2; j++)
#pragma unroll
      for (int r = 0; r < 4; r++) {
        int m = i * 16 + kq * 4 + r;
        int n = wn + j * 16 + lr;
        float v = fmaxf(acc[i][j][r] * iv1[j] + bc1[j], 0.f);
        *(bf16*)(P2 + lds_off(m, n * 2)) = (bf16)v;
      }
  __syncthreads();

  // GEMM4: out = relu(bn2(hmid @ Wv2^T)) + pv
  zero_acc(acc);
  gemm_core(acc, P2, Wv2, lr, kq, wn);
  float iv2[2], bc2[2];
#pragma unroll
  for (int j = 0; j < 2; j++) {
    int c = wn + j * 16 + lr;
    float s = bg2[c] * rsqrtf(bv2[c] + 1e-5f);
    iv2[j] = s;
    bc2[j] = bb2[c] - bm2[c] * s;
  }
#pragma unroll
  for (int i = 0; i < 4; i++)
#pragma unroll
    for (int j = 0; j < 2; j++)
#pragma unroll
      for (int r = 0; r < 4; r++) {
        int m = i * 16 + kq * 4 + r;
        int n = wn + j * 16 + lr;
        float v = fmaxf(acc[i][j][r] * iv2[j] + bc2[j], 0.f) + (float)pvr[i][j][r];
        out[(m0 + m) * DIM + n] = v;
      }
}

extern "C" void kernel_launch(void* const* d_in, const int* in_sizes, int n_in,
                              void* d_out, int out_size, void* d_ws,
                              size_t ws_size, hipStream_t stream) {
  const float* features  = (const float*)d_in[0];
  const float* features2 = (const float*)d_in[1];
  const float* Wk  = (const float*)d_in[2];
  const float* Wv1 = (const float*)d_in[3];
  const float* Wv2 = (const float*)d_in[4];
  const float* g1 = (const float*)d_in[5];
  const float* b1 = (const float*)d_in[6];
  const float* m1 = (const float*)d_in[7];
  const float* v1 = (const float*)d_in[8];
  const float* g2 = (const float*)d_in[9];
  const float* b2 = (const float*)d_in[10];
  const float* m2 = (const float*)d_in[11];
  const float* v2 = (const float*)d_in[12];
  // d_in[13] Wa, d_in[14] Wqk: cancelled, unused.
  const float* Wvc = (const float*)d_in[15];
  float* out = (float*)d_out;

  // ws (bf16): wk | wvc | wv1 | wv2  = 2 MiB total.
  bf16* wkb  = (bf16*)d_ws;
  bf16* wvcb = wkb + (size_t)DIM * DIM;
  bf16* wv1b = wvcb + (size_t)DIM * DIM;
  bf16* wv2b = wv1b + (size_t)DIM * DIM;

  // Single launch converts all 4 weight matrices.
  cvt4_f32_bf16<<<dim3(4 * 256), dim3(256), 0, stream>>>(
      Wk, Wvc, Wv1, Wv2, wkb, wvcb, wv1b, wv2b);

  dim3 grid(NROWS / MBLK);  // 1024 blocks, 1024 threads (16 waves)
  dim3 block(1024);
  fused_all<<<grid, block, 0, stream>>>(features, features2, wkb, wvcb, wv1b,
                                        wv2b, out, g1, b1, m1, v1, g2, b2, m2,
                                        v2);
}

// Round 6
// 608.486 us; speedup vs baseline: 1.0966x; 1.0920x over previous
//
#include <hip/hip_runtime.h>
#include <hip/hip_bf16.h>
#include <cstdint>
#include <cstddef>

// AttentionModule N=65536, C=D=512, L=16.
// Math (L-expand makes softmax uniform; attention branch cancels):
//   pos  = relu(features @ Wk^T)
//   pv   = sigmoid(pos @ Wvc^T) * pos
//   hmid = relu(bn1(features2 @ Wv1^T))
//   out  = relu(bn2(hmid @ Wv2^T)) + pv
//
// Round-6 shape: TWO kernels (the only spill-free structure measured:
// round-2 pair had WRITE==ideal), but with round-5's block shape that
// proved 47% occupancy: 1024 threads / 16 waves, 64-row panel, wave tile
// 64x32 -> ~110 regs incl. AGPR acc, under the 128 cap at 4 waves/SIMD.
//   fusedA: f -> P(LDS), GEMM1(relu)->P, GEMM2 -> pv (packed bf16 ws)
//   fusedB: f2 -> P(LDS), GEMM3(relu.bn1)->P, GEMM4(relu.bn2)+pv -> out
// B fragments stream from global (weights L2-resident bf16); K-loop is
// barrier-free, fully unrolled, mov-free double-buffered (a0/a1, b0/b1).

#define DIM 512
#define NROWS 65536
#define MBLK 64

typedef __bf16 bf16;
typedef __attribute__((ext_vector_type(8))) __bf16 bf16x8;
typedef __attribute__((ext_vector_type(4))) __bf16 bf16x4;
typedef __attribute__((ext_vector_type(4))) float f32x4;

__device__ __forceinline__ float sigmoidf_(float x) {
  return 1.0f / (1.0f + __expf(-x));
}

// Swizzled LDS byte offset into a [64][512] bf16 panel (row stride 1024 B).
// XOR of (row&15)<<4 spreads an MFMA A-fragment's 16 rows across 16 distinct
// 16B slots -> max 2-way bank aliasing on ds_read_b128 (free).
__device__ __forceinline__ int lds_off(int row, int cb) {
  return row * (DIM * 2) + (cb ^ ((row & 15) << 4));
}

// A-fragment read: rows i*16+lr, k-chunk kb + kq*8 elems (16B).
__device__ __forceinline__ bf16x8 lda(const char* As, int i, int lr, int kq,
                                      int kb) {
  return *(const bf16x8*)(As + (i * 16 + lr) * (DIM * 2) +
                          ((kb * 2 + kq * 16) ^ (lr << 4)));
}

// fp32 -> bf16 for the 4 weight matrices in ONE launch.
// grid = 4 * 256 blocks of 256 threads; 65536 x4-chunks per matrix.
__global__ __launch_bounds__(256) void cvt4_f32_bf16(
    const float* __restrict__ s0, const float* __restrict__ s1,
    const float* __restrict__ s2, const float* __restrict__ s3,
    bf16* __restrict__ d0, bf16* __restrict__ d1, bf16* __restrict__ d2,
    bf16* __restrict__ d3) {
  int mat = blockIdx.x >> 8;
  int i = (blockIdx.x & 255) * 256 + threadIdx.x;
  const float* s = mat == 0 ? s0 : mat == 1 ? s1 : mat == 2 ? s2 : s3;
  bf16* d = mat == 0 ? d0 : mat == 1 ? d1 : mat == 2 ? d2 : d3;
  f32x4 v = ((const f32x4*)s)[i];
  bf16x4 o;
  o[0] = (bf16)v[0]; o[1] = (bf16)v[1]; o[2] = (bf16)v[2]; o[3] = (bf16)v[3];
  ((bf16x4*)d)[i] = o;
}

// Stage a 64x512 fp32 panel -> bf16, swizzled, into LDS. 1024 threads.
__device__ __forceinline__ void stage_panel(char* P, const float* __restrict__ g,
                                            int t) {
#pragma unroll
  for (int it = 0; it < 4; ++it) {
    int c = it * 1024 + t;  // 16B-bf16-chunk id, 0..4095
    f32x4 v0 = *(const f32x4*)(g + (size_t)c * 8);
    f32x4 v1 = *(const f32x4*)(g + (size_t)c * 8 + 4);
    bf16x8 o;
    o[0] = (bf16)v0[0]; o[1] = (bf16)v0[1]; o[2] = (bf16)v0[2]; o[3] = (bf16)v0[3];
    o[4] = (bf16)v1[0]; o[5] = (bf16)v1[1]; o[6] = (bf16)v1[2]; o[7] = (bf16)v1[3];
    *(bf16x8*)(P + lds_off(c >> 6, (c & 63) * 16)) = o;
  }
}

// Per-wave 64(M)x32(N) tile: acc += As(64x512 bf16, swizzled) @ W[wn:wn+32,:]^T.
// Mov-free double-buffered pipeline (a0/a1 half-step, b0/b1 one-step ahead).
__device__ __forceinline__ void gemm_core(f32x4 (&acc)[4][2], const char* As,
                                          const bf16* __restrict__ W, int lr,
                                          int kq, int wn) {
  const bf16* bp = W + (size_t)(wn + lr) * DIM + kq * 8;
  bf16x8 a0[4], a1[4], b0[2], b1[2];
#pragma unroll
  for (int j = 0; j < 2; j++) b0[j] = *(const bf16x8*)(bp + j * 16 * DIM);
#pragma unroll
  for (int j = 0; j < 2; j++) b1[j] = *(const bf16x8*)(bp + j * 16 * DIM + 32);
#pragma unroll
  for (int i = 0; i < 4; i++) a0[i] = lda(As, i, lr, kq, 0);
#pragma unroll
  for (int kb = 0; kb < DIM; kb += 64) {
    // ---- half 0: consume a0/b0 (k=kb) ----
#pragma unroll
    for (int i = 0; i < 4; i++) a1[i] = lda(As, i, lr, kq, kb + 32);
#pragma unroll
    for (int i = 0; i < 4; i++)
#pragma unroll
      for (int j = 0; j < 2; j++)
        acc[i][j] = __builtin_amdgcn_mfma_f32_16x16x32_bf16(a0[i], b0[j],
                                                            acc[i][j], 0, 0, 0);
    if (kb + 64 < DIM) {
#pragma unroll
      for (int j = 0; j < 2; j++)
        b0[j] = *(const bf16x8*)(bp + j * 16 * DIM + kb + 64);
#pragma unroll
      for (int i = 0; i < 4; i++) a0[i] = lda(As, i, lr, kq, kb + 64);
    }
    // ---- half 1: consume a1/b1 (k=kb+32) ----
#pragma unroll
    for (int i = 0; i < 4; i++)
#pragma unroll
      for (int j = 0; j < 2; j++)
        acc[i][j] = __builtin_amdgcn_mfma_f32_16x16x32_bf16(a1[i], b1[j],
                                                            acc[i][j], 0, 0, 0);
    if (kb + 96 < DIM) {
#pragma unroll
      for (int j = 0; j < 2; j++)
        b1[j] = *(const bf16x8*)(bp + j * 16 * DIM + kb + 96);
    }
  }
}

__device__ __forceinline__ void zero_acc(f32x4 (&acc)[4][2]) {
#pragma unroll
  for (int i = 0; i < 4; i++)
#pragma unroll
    for (int j = 0; j < 2; j++) acc[i][j] = (f32x4){0.f, 0.f, 0.f, 0.f};
}

// Kernel A: pos = relu(f @ Wk^T); pv = sigmoid(pos @ Wvc^T) * pos -> packed ws.
__global__ __launch_bounds__(1024, 1) void fusedA(
    const float* __restrict__ f, const bf16* __restrict__ Wk,
    const bf16* __restrict__ Wvc, bf16x4* __restrict__ pvws) {
  __shared__ __align__(16) char P[MBLK * DIM * 2];  // 64 KiB

  const int t = threadIdx.x;
  const int lane = t & 63;
  const int lr = lane & 15;
  const int kq = lane >> 4;
  const int wn = (t >> 6) * 32;  // 16 waves x 32 cols = 512
  const size_t m0 = (size_t)blockIdx.x * MBLK;

  stage_panel(P, f + m0 * DIM, t);
  __syncthreads();

  f32x4 acc[4][2];

  // GEMM1: pos = relu(f @ Wk^T)
  zero_acc(acc);
  gemm_core(acc, P, Wk, lr, kq, wn);
  __syncthreads();  // all waves done reading f-panel
#pragma unroll
  for (int i = 0; i < 4; i++)
#pragma unroll
    for (int j = 0; j < 2; j++)
#pragma unroll
      for (int r = 0; r < 4; r++) {
        int m = i * 16 + kq * 4 + r;
        int n = wn + j * 16 + lr;
        *(bf16*)(P + lds_off(m, n * 2)) = (bf16)fmaxf(acc[i][j][r], 0.f);
      }
  __syncthreads();

  // GEMM2: pv = sigmoid(pos @ Wvc^T) * pos  -> packed fragment store
  zero_acc(acc);
  gemm_core(acc, P, Wvc, lr, kq, wn);
#pragma unroll
  for (int i = 0; i < 4; i++)
#pragma unroll
    for (int j = 0; j < 2; j++) {
      bf16x4 o;
#pragma unroll
      for (int r = 0; r < 4; r++) {
        int m = i * 16 + kq * 4 + r;
        int n = wn + j * 16 + lr;
        float p = (float)(*(const bf16*)(P + lds_off(m, n * 2)));
        o[r] = (bf16)(sigmoidf_(acc[i][j][r]) * p);
      }
      // packed per-thread fragment order, lane-contiguous (coalesced 8B/lane)
      pvws[((size_t)blockIdx.x * 8 + i * 2 + j) * 1024 + t] = o;
    }
}

// Kernel B: hmid = relu(bn1(f2 @ Wv1^T)); out = relu(bn2(hmid @ Wv2^T)) + pv.
__global__ __launch_bounds__(1024, 1) void fusedB(
    const float* __restrict__ f2, const bf16* __restrict__ Wv1,
    const bf16* __restrict__ Wv2, const bf16x4* __restrict__ pvws,
    float* __restrict__ out, const float* __restrict__ bg1,
    const float* __restrict__ bb1, const float* __restrict__ bm1,
    const float* __restrict__ bv1, const float* __restrict__ bg2,
    const float* __restrict__ bb2, const float* __restrict__ bm2,
    const float* __restrict__ bv2) {
  __shared__ __align__(16) char P[MBLK * DIM * 2];  // 64 KiB

  const int t = threadIdx.x;
  const int lane = t & 63;
  const int lr = lane & 15;
  const int kq = lane >> 4;
  const int wn = (t >> 6) * 32;
  const size_t m0 = (size_t)blockIdx.x * MBLK;

  stage_panel(P, f2 + m0 * DIM, t);
  __syncthreads();

  f32x4 acc[4][2];

  // GEMM3: hmid = relu(bn1(f2 @ Wv1^T))
  zero_acc(acc);
  gemm_core(acc, P, Wv1, lr, kq, wn);
  float iv1[2], bc1[2];
#pragma unroll
  for (int j = 0; j < 2; j++) {
    int c = wn + j * 16 + lr;
    float s = bg1[c] * rsqrtf(bv1[c] + 1e-5f);
    iv1[j] = s;
    bc1[j] = bb1[c] - bm1[c] * s;
  }
  __syncthreads();  // all waves done reading f2-panel
#pragma unroll
  for (int i = 0; i < 4; i++)
#pragma unroll
    for (int j = 0; j < 2; j++)
#pragma unroll
      for (int r = 0; r < 4; r++) {
        int m = i * 16 + kq * 4 + r;
        int n = wn + j * 16 + lr;
        float v = fmaxf(acc[i][j][r] * iv1[j] + bc1[j], 0.f);
        *(bf16*)(P + lds_off(m, n * 2)) = (bf16)v;
      }
  __syncthreads();

  // GEMM4: out = relu(bn2(hmid @ Wv2^T)) + pv
  zero_acc(acc);
  gemm_core(acc, P, Wv2, lr, kq, wn);
  float iv2[2], bc2[2];
#pragma unroll
  for (int j = 0; j < 2; j++) {
    int c = wn + j * 16 + lr;
    float s = bg2[c] * rsqrtf(bv2[c] + 1e-5f);
    iv2[j] = s;
    bc2[j] = bb2[c] - bm2[c] * s;
  }
#pragma unroll
  for (int i = 0; i < 4; i++)
#pragma unroll
    for (int j = 0; j < 2; j++) {
      bf16x4 pv = pvws[((size_t)blockIdx.x * 8 + i * 2 + j) * 1024 + t];
#pragma unroll
      for (int r = 0; r < 4; r++) {
        int m = i * 16 + kq * 4 + r;
        int n = wn + j * 16 + lr;
        float v = fmaxf(acc[i][j][r] * iv2[j] + bc2[j], 0.f) + (float)pv[r];
        out[(m0 + m) * DIM + n] = v;
      }
    }
}

extern "C" void kernel_launch(void* const* d_in, const int* in_sizes, int n_in,
                              void* d_out, int out_size, void* d_ws,
                              size_t ws_size, hipStream_t stream) {
  const float* features  = (const float*)d_in[0];
  const float* features2 = (const float*)d_in[1];
  const float* Wk  = (const float*)d_in[2];
  const float* Wv1 = (const float*)d_in[3];
  const float* Wv2 = (const float*)d_in[4];
  const float* g1 = (const float*)d_in[5];
  const float* b1 = (const float*)d_in[6];
  const float* m1 = (const float*)d_in[7];
  const float* v1 = (const float*)d_in[8];
  const float* g2 = (const float*)d_in[9];
  const float* b2 = (const float*)d_in[10];
  const float* m2 = (const float*)d_in[11];
  const float* v2 = (const float*)d_in[12];
  // d_in[13] Wa, d_in[14] Wqk: cancelled, unused.
  const float* Wvc = (const float*)d_in[15];
  float* out = (float*)d_out;

  // ws (bf16): wk | wvc | wv1 | wv2 | pv(packed)  ~= 66 MiB total.
  bf16* wkb  = (bf16*)d_ws;
  bf16* wvcb = wkb + (size_t)DIM * DIM;
  bf16* wv1b = wvcb + (size_t)DIM * DIM;
  bf16* wv2b = wv1b + (size_t)DIM * DIM;
  bf16* pvws = wv2b + (size_t)DIM * DIM;

  // Single launch converts all 4 weight matrices.
  cvt4_f32_bf16<<<dim3(4 * 256), dim3(256), 0, stream>>>(
      Wk, Wvc, Wv1, Wv2, wkb, wvcb, wv1b, wv2b);

  dim3 grid(NROWS / MBLK);  // 1024 blocks, 1024 threads (16 waves)
  dim3 block(1024);
  fusedA<<<grid, block, 0, stream>>>(features, wkb, wvcb, (bf16x4*)pvws);
  fusedB<<<grid, block, 0, stream>>>(features2, wv1b, wv2b,
                                     (const bf16x4*)pvws, out,
                                     g1, b1, m1, v1, g2, b2, m2, v2);
}